// Round 14
// baseline (81.842 us; speedup 1.0000x reference)
//
#include <hip/hip_runtime.h>

// CharRNN GRU: B=4096, T=256, V=256, H=20, L=15, reset_after=True, drop_rate=0.
// f32 in / f32 out. 3 batches per wave (20 lanes each), 1366 one-wave blocks.
// Dot engine = v_pk_fma_f32 (FULL-rate, 2 MACs/2cyc) replacing quarter-rate
// v_dot2_f32_bf16 (R10-fit: dot2/trans issue at ~8cyc/wave64 -> 30 dots were
// ~240 cyc/step). h transported as f32 (ds_write_b32 + 5x ds_read_b128),
// software-pipelined across the backedge with staged counted waits
// (lgkmcnt 4/2/0, "+v"-tied + sched_barrier, rule-18-safe). U as 30 f32
// pairs in 60 VGPRs. Activations exp2-folded (log2e pre-scaled into tables).

#define BB 4096
#define TT 256
#define VV 256
#define HH 20
#define G3 60    // 3*H
#define LL 15
#define L2E 1.44269504088896340736f

typedef float f32x4 __attribute__((ext_vector_type(4)));
typedef float f32x2 __attribute__((ext_vector_type(2)));

static __device__ __forceinline__ float fast_rcp(float x) {
#if __has_builtin(__builtin_amdgcn_rcpf)
    return __builtin_amdgcn_rcpf(x);
#else
    return 1.0f / x;
#endif
}
// packed fp32 FMA: d = a*b + c on both lanes of the pair (full-rate VOP3P)
static __device__ __forceinline__ f32x2 pkfma(f32x2 a, f32x2 b, f32x2 c) {
    f32x2 d;
    asm("v_pk_fma_f32 %0, %1, %2, %3" : "=v"(d) : "v"(a), "v"(b), "v"(c));
    return d;
}
static __device__ __forceinline__ float exp2i(float x) {
    float r; asm("v_exp_f32 %0, %1" : "=v"(r) : "v"(x)); return r;
}
static __device__ __forceinline__ f32x2 lo2(f32x4 v) {
    return __builtin_shufflevector(v, v, 0, 1);
}
static __device__ __forceinline__ f32x2 hi2(f32x4 v) {
    return __builtin_shufflevector(v, v, 2, 3);
}

// issue exchange for the NEXT step: write my f32 h, queue 5 reads (80 B).
// NO wait here -- RT hides under loop glue + next iteration's prefetch.
static __device__ __forceinline__ void exch_issue(unsigned waddr, float h,
                                                  unsigned raddr,
                                                  f32x4& p0, f32x4& p1, f32x4& p2,
                                                  f32x4& p3, f32x4& p4) {
    asm volatile(
        "ds_write_b32 %5, %6\n\t"
        "ds_read_b128 %0, %7\n\t"
        "ds_read_b128 %1, %7 offset:16\n\t"
        "ds_read_b128 %2, %7 offset:32\n\t"
        "ds_read_b128 %3, %7 offset:48\n\t"
        "ds_read_b128 %4, %7 offset:64"
        : "=&v"(p0), "=&v"(p1), "=&v"(p2), "=&v"(p3), "=&v"(p4)
        : "v"(waddr), "v"(h), "v"(raddr));
}
// staged counted waits; ties make consumers data-dependent (no hoisting).
static __device__ __forceinline__ void wait_s1(f32x4& p0) {
    asm volatile("s_waitcnt lgkmcnt(4)" : "+v"(p0));   // write+read0 retired
    __builtin_amdgcn_sched_barrier(0);
}
static __device__ __forceinline__ void wait_s2(f32x4& p1, f32x4& p2) {
    asm volatile("s_waitcnt lgkmcnt(2)" : "+v"(p1), "+v"(p2));
    __builtin_amdgcn_sched_barrier(0);
}
static __device__ __forceinline__ void wait_s3(f32x4& p3, f32x4& p4) {
    asm volatile("s_waitcnt lgkmcnt(0)" : "+v"(p3), "+v"(p4));
    __builtin_amdgcn_sched_barrier(0);
}

__global__ __launch_bounds__(64, 2) void gru_kernel(
    const int* __restrict__ x,            // [B][T] int32
    const float* __restrict__ kernelW,    // [V][3H] f32
    const float* __restrict__ rkernel,    // [H][3H] f32
    const float* __restrict__ bias,       // [2][3H] f32
    const float* __restrict__ dense_w,    // [H][L] f32
    const float* __restrict__ dense_b,    // [L] f32
    float* __restrict__ out)              // [B][L] f32
{
    // 3 groups * 80 B (20 f32) + 16 B idle-lane scratch = 272 B LDS
    __shared__ __align__(16) float hbuf[68];

    const int lane = threadIdx.x;          // one wave per block
    const int g3a  = lane / 20;            // 0,1,2 active; 3 for lanes 60-63
    const int g3   = (lane < 60) ? g3a : 0;
    const int j    = lane - g3a * 20;      // 0..19 (idle lanes: 0..3)
    const bool active = (lane < 60);
    const long b  = (long)blockIdx.x * 3 + g3;
    const long bc = (b < BB) ? b : (BB - 1);   // clamped for loads

    const unsigned hbase = (unsigned)(size_t)&hbuf[0];
    const unsigned waddr = active ? (hbase + 80u * (unsigned)g3a + 4u * (unsigned)j)
                                  : (hbase + 240u + 4u * (unsigned)(lane - 60));
    const unsigned raddr = hbase + 80u * (unsigned)g3;

    // U columns j, H+j, 2H+j as f32 pairs over i (60 VGPRs), pre-scaled:
    // z/r by -log2e (sigmoid via exp2), h by +2log2e (tanh via exp2)
    f32x2 Uz[10], Ur[10], Uh[10];
    #pragma unroll
    for (int q = 0; q < 10; ++q) {
        Uz[q] = f32x2{ rkernel[(2*q)*G3 + j]        * (-L2E),
                       rkernel[(2*q+1)*G3 + j]      * (-L2E) };
        Ur[q] = f32x2{ rkernel[(2*q)*G3 + HH + j]   * (-L2E),
                       rkernel[(2*q+1)*G3 + HH + j] * (-L2E) };
        Uh[q] = f32x2{ rkernel[(2*q)*G3 + 2*HH + j]   * (2.0f*L2E),
                       rkernel[(2*q+1)*G3 + 2*HH + j] * (2.0f*L2E) };
    }
    // z/r: input+recurrent biases additive -> one folded constant each.
    const float bzc = (bias[j]        + bias[G3 + j])      * (-L2E);
    const float brc = (bias[HH + j]   + bias[G3 + HH + j]) * (-L2E);
    const float bhi =  bias[2*HH + j]                      * (2.0f*L2E);
    const float brh =  bias[G3 + 2*HH + j]                 * (2.0f*L2E);

    const int* xrow = x + bc * TT;

    // prologue: fold x-part for t=0, prefetch xv for t=1
    const int xv0 = xrow[0];
    const float* kw0 = kernelW + xv0 * G3;
    float cz = fmaf(kw0[j],        -L2E,     bzc);
    float cr = fmaf(kw0[HH + j],   -L2E,     brc);
    float ch = fmaf(kw0[2*HH + j], 2.0f*L2E, bhi);
    int xvA = xrow[1];

    float hm = 0.0f;
    f32x4 p0, p1, p2, p3, p4;
    exch_issue(waddr, 0.0f, raddr, p0, p1, p2, p3, p4);   // transport h(0)=0

    for (int t = 0; t < TT; ++t) {
        // ---- prefetch (vmcnt, off-chain): kW(t+1) via xvA, xv(t+2)
        const float* kwn = kernelW + xvA * G3;
        const float lz = kwn[j];
        const float lr = kwn[HH + j];
        const float lh = kwn[2*HH + j];
        const int xvB = xrow[(t + 2 < TT) ? (t + 2) : (TT - 1)];

        // ---- stage 1: pairs 0-1 ready -> start chains (reads 2-5 in flight)
        wait_s1(p0);
        f32x2 za = f32x2{cz, 0.f}, ra = f32x2{cr, 0.f}, ha = f32x2{brh, 0.f};
        {
            const f32x2 q0 = lo2(p0), q1 = hi2(p0);
            za = pkfma(q0, Uz[0], za); ra = pkfma(q0, Ur[0], ra); ha = pkfma(q0, Uh[0], ha);
            za = pkfma(q1, Uz[1], za); ra = pkfma(q1, Ur[1], ra); ha = pkfma(q1, Uh[1], ha);
        }
        // ---- stage 2: pairs 2-5
        wait_s2(p1, p2);
        f32x2 zb = f32x2{0.f, 0.f}, rb = f32x2{0.f, 0.f}, hb = f32x2{0.f, 0.f};
        {
            const f32x2 q2 = lo2(p1), q3 = hi2(p1), q4 = lo2(p2), q5 = hi2(p2);
            za = pkfma(q2, Uz[2], za); ra = pkfma(q2, Ur[2], ra); ha = pkfma(q2, Uh[2], ha);
            za = pkfma(q3, Uz[3], za); ra = pkfma(q3, Ur[3], ra); ha = pkfma(q3, Uh[3], ha);
            za = pkfma(q4, Uz[4], za); ra = pkfma(q4, Ur[4], ra); ha = pkfma(q4, Uh[4], ha);
            zb = pkfma(q5, Uz[5], zb); rb = pkfma(q5, Ur[5], rb); hb = pkfma(q5, Uh[5], hb);
        }
        // ---- stage 3: pairs 6-9
        wait_s3(p3, p4);
        {
            const f32x2 q6 = lo2(p3), q7 = hi2(p3), q8 = lo2(p4), q9 = hi2(p4);
            zb = pkfma(q6, Uz[6], zb); rb = pkfma(q6, Ur[6], rb); hb = pkfma(q6, Uh[6], hb);
            zb = pkfma(q7, Uz[7], zb); rb = pkfma(q7, Ur[7], rb); hb = pkfma(q7, Uh[7], hb);
            zb = pkfma(q8, Uz[8], zb); rb = pkfma(q8, Ur[8], rb); hb = pkfma(q8, Uh[8], hb);
            zb = pkfma(q9, Uz[9], zb); rb = pkfma(q9, Ur[9], rb); hb = pkfma(q9, Uh[9], hb);
        }

        // ---- horizontal sums (pk add + scalar add)
        const f32x2 zs = za + zb, rs = ra + rb, hs = ha + hb;
        const float z_in = zs.x + zs.y;
        const float r_in = rs.x + rs.y;
        const float h_in = hs.x + hs.y;

        // ---- folded activations (one v_exp + one v_rcp each)
        const float r  = fast_rcp(1.0f + exp2i(r_in));             // sigmoid
        const float z  = fast_rcp(1.0f + exp2i(z_in));             // sigmoid
        const float yh = fmaf(r, h_in, ch);                        // 2log2e-scaled
        const float hc = fmaf(-2.0f, fast_rcp(1.0f + exp2i(yh)), 1.0f); // tanh
        hm = hc + z * (hm - hc);

        // ---- ISSUE next step's exchange (RT hides under glue + prefetch)
        exch_issue(waddr, hm, raddr, p0, p1, p2, p3, p4);

        // ---- commit prefetched folds for t+1
        cz = fmaf(lz, -L2E,     bzc);
        cr = fmaf(lr, -L2E,     brc);
        ch = fmaf(lh, 2.0f*L2E, bhi);
        xvA = xvB;
    }

    // ---- final exchange (issued at t=255 bottom) carries h(256), f32
    asm volatile("s_waitcnt lgkmcnt(0)"
                 : "+v"(p0), "+v"(p1), "+v"(p2), "+v"(p3), "+v"(p4));
    __builtin_amdgcn_sched_barrier(0);
    const float hf[HH] = { p0.x, p0.y, p0.z, p0.w,  p1.x, p1.y, p1.z, p1.w,
                           p2.x, p2.y, p2.z, p2.w,  p3.x, p3.y, p3.z, p3.w,
                           p4.x, p4.y, p4.z, p4.w };

    // ---- dense head: logits[b][l] = db[l] + sum_i h[i] * W[i][l]
    if (active && j < LL && b < BB) {
        float acc = dense_b[j];
        #pragma unroll
        for (int i = 0; i < HH; ++i)
            acc = fmaf(hf[i], dense_w[i * LL + j], acc);
        out[b * LL + j] = acc;
    }
}

extern "C" void kernel_launch(void* const* d_in, const int* in_sizes, int n_in,
                              void* d_out, int out_size, void* d_ws, size_t ws_size,
                              hipStream_t stream) {
    const int* x            = (const int*)d_in[0];
    // d_in[1] = drop_rate (0.0f) -> dropout is identity; ignored.
    const float* kernelW    = (const float*)d_in[2];
    const float* rkernel    = (const float*)d_in[3];
    const float* bias       = (const float*)d_in[4];
    const float* dense_w    = (const float*)d_in[5];
    const float* dense_b    = (const float*)d_in[6];
    float* out              = (float*)d_out;

    dim3 grid((BB + 2) / 3);   // 1366 one-wave blocks, 3 batches each
    dim3 block(64);
    gru_kernel<<<grid, block, 0, stream>>>(x, kernelW, rkernel, bias,
                                           dense_w, dense_b, out);
}

// Round 15
// 81.619 us; speedup vs baseline: 1.0027x; 1.0027x over previous
//
#include <hip/hip_runtime.h>

// CharRNN GRU: B=4096, T=256, V=256, H=20, L=15, reset_after=True, drop_rate=0.
// f32 in / f32 out. 3 batches per wave (20 lanes each), 1366 one-wave blocks.
// R14 structure (v_pk_fma_f32 dots, f32 h transport, pipelined exchange with
// staged counted lgkm waits) + THE FIX: U is pinned register-resident with
// zero-instruction empty-asm "+v" pins INSIDE the loop. R7-R14 all silently
// re-fetched U from global every step (VGPR_Count 36-56 < U footprint);
// LLVM remat treats invariant loads as free and sinks them regardless of
// the occupancy budget. Pins make remat pointless and cannot be hoisted.

#define BB 4096
#define TT 256
#define VV 256
#define HH 20
#define G3 60    // 3*H
#define LL 15
#define L2E 1.44269504088896340736f

typedef float f32x4 __attribute__((ext_vector_type(4)));
typedef float f32x2 __attribute__((ext_vector_type(2)));

static __device__ __forceinline__ float fast_rcp(float x) {
#if __has_builtin(__builtin_amdgcn_rcpf)
    return __builtin_amdgcn_rcpf(x);
#else
    return 1.0f / x;
#endif
}
// packed fp32 FMA: d = a*b + c on both halves (VOP3P)
static __device__ __forceinline__ f32x2 pkfma(f32x2 a, f32x2 b, f32x2 c) {
    f32x2 d;
    asm("v_pk_fma_f32 %0, %1, %2, %3" : "=v"(d) : "v"(a), "v"(b), "v"(c));
    return d;
}
static __device__ __forceinline__ float exp2i(float x) {
    float r; asm("v_exp_f32 %0, %1" : "=v"(r) : "v"(x)); return r;
}
static __device__ __forceinline__ f32x2 lo2(f32x4 v) {
    return __builtin_shufflevector(v, v, 0, 1);
}
static __device__ __forceinline__ f32x2 hi2(f32x4 v) {
    return __builtin_shufflevector(v, v, 2, 3);
}

// issue exchange for the NEXT step: write my f32 h, queue 5 reads (80 B).
static __device__ __forceinline__ void exch_issue(unsigned waddr, float h,
                                                  unsigned raddr,
                                                  f32x4& p0, f32x4& p1, f32x4& p2,
                                                  f32x4& p3, f32x4& p4) {
    asm volatile(
        "ds_write_b32 %5, %6\n\t"
        "ds_read_b128 %0, %7\n\t"
        "ds_read_b128 %1, %7 offset:16\n\t"
        "ds_read_b128 %2, %7 offset:32\n\t"
        "ds_read_b128 %3, %7 offset:48\n\t"
        "ds_read_b128 %4, %7 offset:64"
        : "=&v"(p0), "=&v"(p1), "=&v"(p2), "=&v"(p3), "=&v"(p4)
        : "v"(waddr), "v"(h), "v"(raddr));
}
// staged counted waits; ties make consumers data-dependent (no hoisting).
static __device__ __forceinline__ void wait_s1(f32x4& p0) {
    asm volatile("s_waitcnt lgkmcnt(4)" : "+v"(p0));   // write+read0 retired
    __builtin_amdgcn_sched_barrier(0);
}
static __device__ __forceinline__ void wait_s2(f32x4& p1, f32x4& p2) {
    asm volatile("s_waitcnt lgkmcnt(2)" : "+v"(p1), "+v"(p2));
    __builtin_amdgcn_sched_barrier(0);
}
static __device__ __forceinline__ void wait_s3(f32x4& p3, f32x4& p4) {
    asm volatile("s_waitcnt lgkmcnt(0)" : "+v"(p3), "+v"(p4));
    __builtin_amdgcn_sched_barrier(0);
}

__global__ __launch_bounds__(64, 1) void gru_kernel(
    const int* __restrict__ x,            // [B][T] int32
    const float* __restrict__ kernelW,    // [V][3H] f32
    const float* __restrict__ rkernel,    // [H][3H] f32
    const float* __restrict__ bias,       // [2][3H] f32
    const float* __restrict__ dense_w,    // [H][L] f32
    const float* __restrict__ dense_b,    // [L] f32
    float* __restrict__ out)              // [B][L] f32
{
    // 3 groups * 80 B (20 f32) + 16 B idle-lane scratch = 272 B LDS
    __shared__ __align__(16) float hbuf[68];

    const int lane = threadIdx.x;          // one wave per block
    const int g3a  = lane / 20;            // 0,1,2 active; 3 for lanes 60-63
    const int g3   = (lane < 60) ? g3a : 0;
    const int j    = lane - g3a * 20;      // 0..19 (idle lanes: 0..3)
    const bool active = (lane < 60);
    const long b  = (long)blockIdx.x * 3 + g3;
    const long bc = (b < BB) ? b : (BB - 1);   // clamped for loads

    const unsigned hbase = (unsigned)(size_t)&hbuf[0];
    const unsigned waddr = active ? (hbase + 80u * (unsigned)g3a + 4u * (unsigned)j)
                                  : (hbase + 240u + 4u * (unsigned)(lane - 60));
    const unsigned raddr = hbase + 80u * (unsigned)g3;

    // U columns j, H+j, 2H+j as f32 pairs over i (60 VGPRs), pre-scaled:
    // z/r by -log2e (sigmoid via exp2), h by +2log2e (tanh via exp2)
    f32x2 Uz[10], Ur[10], Uh[10];
    #pragma unroll
    for (int q = 0; q < 10; ++q) {
        Uz[q] = f32x2{ rkernel[(2*q)*G3 + j]        * (-L2E),
                       rkernel[(2*q+1)*G3 + j]      * (-L2E) };
        Ur[q] = f32x2{ rkernel[(2*q)*G3 + HH + j]   * (-L2E),
                       rkernel[(2*q+1)*G3 + HH + j] * (-L2E) };
        Uh[q] = f32x2{ rkernel[(2*q)*G3 + 2*HH + j]   * (2.0f*L2E),
                       rkernel[(2*q+1)*G3 + 2*HH + j] * (2.0f*L2E) };
    }
    // z/r: input+recurrent biases additive -> one folded constant each.
    const float bzc = (bias[j]        + bias[G3 + j])      * (-L2E);
    const float brc = (bias[HH + j]   + bias[G3 + HH + j]) * (-L2E);
    const float bhi =  bias[2*HH + j]                      * (2.0f*L2E);
    const float brh =  bias[G3 + 2*HH + j]                 * (2.0f*L2E);

    const int* xrow = x + bc * TT;

    // prologue: fold x-part for t=0, prefetch xv for t=1
    const int xv0 = xrow[0];
    const float* kw0 = kernelW + xv0 * G3;
    float cz = fmaf(kw0[j],        -L2E,     bzc);
    float cr = fmaf(kw0[HH + j],   -L2E,     brc);
    float ch = fmaf(kw0[2*HH + j], 2.0f*L2E, bhi);
    int xvA = xrow[1];

    float hm = 0.0f;
    f32x4 p0, p1, p2, p3, p4;
    exch_issue(waddr, 0.0f, raddr, p0, p1, p2, p3, p4);   // transport h(0)=0

    for (int t = 0; t < TT; ++t) {
        // ---- THE PIN: zero-instruction, forces U in VGPRs every iteration.
        // Remat can no longer reduce pressure -> allocator keeps U resident.
        #pragma unroll
        for (int q = 0; q < 10; ++q)
            asm volatile("" : "+v"(Uz[q]), "+v"(Ur[q]), "+v"(Uh[q]));

        // ---- prefetch (vmcnt, off-chain): kW(t+1) via xvA, xv(t+2)
        const float* kwn = kernelW + xvA * G3;
        const float lz = kwn[j];
        const float lr = kwn[HH + j];
        const float lh = kwn[2*HH + j];
        const int xvB = xrow[(t + 2 < TT) ? (t + 2) : (TT - 1)];

        // ---- stage 1: pairs 0-1 ready -> start chains (reads 2-5 in flight)
        wait_s1(p0);
        f32x2 za = f32x2{cz, 0.f}, ra = f32x2{cr, 0.f}, ha = f32x2{brh, 0.f};
        {
            const f32x2 q0 = lo2(p0), q1 = hi2(p0);
            za = pkfma(q0, Uz[0], za); ra = pkfma(q0, Ur[0], ra); ha = pkfma(q0, Uh[0], ha);
            za = pkfma(q1, Uz[1], za); ra = pkfma(q1, Ur[1], ra); ha = pkfma(q1, Uh[1], ha);
        }
        // ---- stage 2: pairs 2-5
        wait_s2(p1, p2);
        f32x2 zb = f32x2{0.f, 0.f}, rb = f32x2{0.f, 0.f}, hb = f32x2{0.f, 0.f};
        {
            const f32x2 q2 = lo2(p1), q3 = hi2(p1), q4 = lo2(p2), q5 = hi2(p2);
            za = pkfma(q2, Uz[2], za); ra = pkfma(q2, Ur[2], ra); ha = pkfma(q2, Uh[2], ha);
            za = pkfma(q3, Uz[3], za); ra = pkfma(q3, Ur[3], ra); ha = pkfma(q3, Uh[3], ha);
            za = pkfma(q4, Uz[4], za); ra = pkfma(q4, Ur[4], ra); ha = pkfma(q4, Uh[4], ha);
            zb = pkfma(q5, Uz[5], zb); rb = pkfma(q5, Ur[5], rb); hb = pkfma(q5, Uh[5], hb);
        }
        // ---- stage 3: pairs 6-9
        wait_s3(p3, p4);
        {
            const f32x2 q6 = lo2(p3), q7 = hi2(p3), q8 = lo2(p4), q9 = hi2(p4);
            zb = pkfma(q6, Uz[6], zb); rb = pkfma(q6, Ur[6], rb); hb = pkfma(q6, Uh[6], hb);
            zb = pkfma(q7, Uz[7], zb); rb = pkfma(q7, Ur[7], rb); hb = pkfma(q7, Uh[7], hb);
            zb = pkfma(q8, Uz[8], zb); rb = pkfma(q8, Ur[8], rb); hb = pkfma(q8, Uh[8], hb);
            zb = pkfma(q9, Uz[9], zb); rb = pkfma(q9, Ur[9], rb); hb = pkfma(q9, Uh[9], hb);
        }

        // ---- horizontal sums
        const f32x2 zs = za + zb, rs = ra + rb, hs = ha + hb;
        const float z_in = zs.x + zs.y;
        const float r_in = rs.x + rs.y;
        const float h_in = hs.x + hs.y;

        // ---- folded activations (one v_exp + one v_rcp each)
        const float r  = fast_rcp(1.0f + exp2i(r_in));             // sigmoid
        const float z  = fast_rcp(1.0f + exp2i(z_in));             // sigmoid
        const float yh = fmaf(r, h_in, ch);                        // 2log2e-scaled
        const float hc = fmaf(-2.0f, fast_rcp(1.0f + exp2i(yh)), 1.0f); // tanh
        hm = hc + z * (hm - hc);

        // ---- ISSUE next step's exchange (RT hides under glue + prefetch)
        exch_issue(waddr, hm, raddr, p0, p1, p2, p3, p4);

        // ---- commit prefetched folds for t+1
        cz = fmaf(lz, -L2E,     bzc);
        cr = fmaf(lr, -L2E,     brc);
        ch = fmaf(lh, 2.0f*L2E, bhi);
        xvA = xvB;
    }

    // ---- final exchange (issued at t=255 bottom) carries h(256), f32
    asm volatile("s_waitcnt lgkmcnt(0)"
                 : "+v"(p0), "+v"(p1), "+v"(p2), "+v"(p3), "+v"(p4));
    __builtin_amdgcn_sched_barrier(0);
    const float hf[HH] = { p0.x, p0.y, p0.z, p0.w,  p1.x, p1.y, p1.z, p1.w,
                           p2.x, p2.y, p2.z, p2.w,  p3.x, p3.y, p3.z, p3.w,
                           p4.x, p4.y, p4.z, p4.w };

    // ---- dense head: logits[b][l] = db[l] + sum_i h[i] * W[i][l]
    if (active && j < LL && b < BB) {
        float acc = dense_b[j];
        #pragma unroll
        for (int i = 0; i < HH; ++i)
            acc = fmaf(hf[i], dense_w[i * LL + j], acc);
        out[b * LL + j] = acc;
    }
}

extern "C" void kernel_launch(void* const* d_in, const int* in_sizes, int n_in,
                              void* d_out, int out_size, void* d_ws, size_t ws_size,
                              hipStream_t stream) {
    const int* x            = (const int*)d_in[0];
    // d_in[1] = drop_rate (0.0f) -> dropout is identity; ignored.
    const float* kernelW    = (const float*)d_in[2];
    const float* rkernel    = (const float*)d_in[3];
    const float* bias       = (const float*)d_in[4];
    const float* dense_w    = (const float*)d_in[5];
    const float* dense_b    = (const float*)d_in[6];
    float* out              = (float*)d_out;

    dim3 grid((BB + 2) / 3);   // 1366 one-wave blocks, 3 batches each
    dim3 block(64);
    gru_kernel<<<grid, block, 0, stream>>>(x, kernelW, rkernel, bias,
                                           dense_w, dense_b, out);
}

// Round 16
// 78.306 us; speedup vs baseline: 1.0452x; 1.0423x over previous
//
#include <hip/hip_runtime.h>

// CharRNN GRU: B=4096, T=256, V=256, H=20, L=15, reset_after=True, drop_rate=0.
// f32 in / f32 out. 3 batches per wave (20 lanes each), 1366 one-wave blocks.
// Loop body == R13 (best: pipelined bf16 h-exchange across the backedge with
// counted lgkm waits, v_dot2_f32_bf16 chains, exp2-folded activations).
// NEW: U (30 packed bf16 pairs) + 4 folded bias constants are produced by
// one-time VOLATILE asm ds_reads from an LDS-staged table -> the compiler
// CANNOT rematerialize them (opaque asm), so they must stay VGPR-resident
// (launch_bounds(64,1): 256-VGPR budget, ~75 live, spill unprofitable).
// R6-R15 silently re-fetched U from global every step (VGPR_Count 36-56).

#define BB 4096
#define TT 256
#define VV 256
#define HH 20
#define G3 60    // 3*H
#define LL 15
#define L2E 1.44269504088896340736f

typedef int v4i __attribute__((ext_vector_type(4)));
typedef int v2i __attribute__((ext_vector_type(2)));

static __device__ __forceinline__ unsigned short f2bf(float f) {
    union { float f; unsigned int i; } c; c.f = f;
    unsigned int x = c.i;
    return (unsigned short)((x + 0x7FFFu + ((x >> 16) & 1u)) >> 16); // RNE
}
static __device__ __forceinline__ unsigned pack2bf(float a, float b) {
    return (unsigned)f2bf(a) | ((unsigned)f2bf(b) << 16);
}
static __device__ __forceinline__ float fast_rcp(float x) {
#if __has_builtin(__builtin_amdgcn_rcpf)
    return __builtin_amdgcn_rcpf(x);
#else
    return 1.0f / x;
#endif
}
// D = a.x*b.x + a.y*b.y + c  (bf16 pairs packed in u32, f32 accumulate)
static __device__ __forceinline__ float dot2bf(unsigned a, unsigned b, float c) {
    float d;
    asm("v_dot2_f32_bf16 %0, %1, %2, %3" : "=v"(d) : "v"(a), "v"(b), "v"(c));
    return d;
}
static __device__ __forceinline__ unsigned cvtpk(float lo, float hi) {
    unsigned r;
    asm("v_cvt_pk_bf16_f32 %0, %1, %2" : "=v"(r) : "v"(lo), "v"(hi));
    return r;
}
static __device__ __forceinline__ float exp2i(float x) {
    float r; asm("v_exp_f32 %0, %1" : "=v"(r) : "v"(x)); return r;
}

// issue exchange for the NEXT step: write my bf16 h, queue the 3 reads.
static __device__ __forceinline__ void exch_issue(unsigned waddr, unsigned hbf,
                                                  unsigned raddr,
                                                  v4i& p0, v4i& p1, v2i& p2) {
    asm volatile(
        "ds_write_b16 %3, %4\n\t"
        "ds_read_b128 %0, %5\n\t"
        "ds_read_b128 %1, %5 offset:16\n\t"
        "ds_read_b64 %2, %5 offset:32"
        : "=&v"(p0), "=&v"(p1), "=&v"(p2)
        : "v"(waddr), "v"(hbf), "v"(raddr));
}
static __device__ __forceinline__ void exch_wait_first(v4i& p0) {
    asm volatile("s_waitcnt lgkmcnt(2)" : "+v"(p0));   // write+read0 retired
    __builtin_amdgcn_sched_barrier(0);
}
static __device__ __forceinline__ void exch_wait_rest(v4i& p1, v2i& p2) {
    asm volatile("s_waitcnt lgkmcnt(0)" : "+v"(p1), "+v"(p2));
    __builtin_amdgcn_sched_barrier(0);
}

__global__ __launch_bounds__(64, 1) void gru_kernel(
    const int* __restrict__ x,            // [B][T] int32
    const float* __restrict__ kernelW,    // [V][3H] f32
    const float* __restrict__ rkernel,    // [H][3H] f32
    const float* __restrict__ bias,       // [2][3H] f32
    const float* __restrict__ dense_w,    // [H][L] f32
    const float* __restrict__ dense_b,    // [L] f32
    float* __restrict__ out)              // [B][L] f32
{
    __shared__ __align__(16) unsigned short hbuf[80];  // 160 B h exchange
    // U table: words [0..599] = packed bf16 pairs, idx=(kind*10+q)*20+j
    //          words [600..679] = folded bias f32, idx=600+k*20+j
    __shared__ __align__(16) unsigned utab[680];

    const int lane = threadIdx.x;          // one wave per block
    const int g3a  = lane / 20;            // 0,1,2 active; 3 for lanes 60-63
    const int g3   = (lane < 60) ? g3a : 0;
    const int j    = lane - g3a * 20;      // 0..19 (idle lanes: 0..3)
    const bool active = (lane < 60);
    const long b  = (long)blockIdx.x * 3 + g3;
    const long bc = (b < BB) ? b : (BB - 1);   // clamped for loads

    // ---- stage the pre-scaled tables into LDS (one-time) ----
    for (int idx = lane; idx < 680; idx += 64) {
        float v;
        if (idx < 600) {
            const int kind = idx / 200, rem = idx - kind * 200;
            const int q = rem / 20, jj = rem - q * 20;
            const int off = kind * HH;                      // 0, H, 2H
            const float sc = (kind == 2) ? (2.0f * L2E) : (-L2E);
            utab[idx] = pack2bf(rkernel[(2*q)*G3 + off + jj]   * sc,
                                rkernel[(2*q+1)*G3 + off + jj] * sc);
            continue;
        }
        const int k = (idx - 600) / 20, jj = (idx - 600) - k * 20;
        if      (k == 0) v = (bias[jj]      + bias[G3 + jj])      * (-L2E);
        else if (k == 1) v = (bias[HH + jj] + bias[G3 + HH + jj]) * (-L2E);
        else if (k == 2) v = bias[2*HH + jj]                      * (2.0f*L2E);
        else             v = bias[G3 + 2*HH + jj]                 * (2.0f*L2E);
        utab[idx] = __float_as_uint(v);
    }
    // single wave: DS pipe is in-order, volatile asm reads below see the
    // writes; "memory" clobber stops the compiler sinking stores past them.

    const unsigned ubase = (unsigned)(size_t)&utab[0] + 4u * (unsigned)j;

    // ---- one-time opaque register fill: U pairs + bias constants ----
    unsigned Uz[10], Ur[10], Uh[10];
    asm volatile(
        "ds_read_b32 %0, %20 offset:0\n\t"   "ds_read_b32 %1, %20 offset:80\n\t"
        "ds_read_b32 %2, %20 offset:160\n\t" "ds_read_b32 %3, %20 offset:240\n\t"
        "ds_read_b32 %4, %20 offset:320\n\t" "ds_read_b32 %5, %20 offset:400\n\t"
        "ds_read_b32 %6, %20 offset:480\n\t" "ds_read_b32 %7, %20 offset:560\n\t"
        "ds_read_b32 %8, %20 offset:640\n\t" "ds_read_b32 %9, %20 offset:720\n\t"
        "ds_read_b32 %10, %20 offset:800\n\t" "ds_read_b32 %11, %20 offset:880\n\t"
        "ds_read_b32 %12, %20 offset:960\n\t" "ds_read_b32 %13, %20 offset:1040\n\t"
        "ds_read_b32 %14, %20 offset:1120\n\t" "ds_read_b32 %15, %20 offset:1200\n\t"
        "ds_read_b32 %16, %20 offset:1280\n\t" "ds_read_b32 %17, %20 offset:1360\n\t"
        "ds_read_b32 %18, %20 offset:1440\n\t" "ds_read_b32 %19, %20 offset:1520"
        : "=&v"(Uz[0]), "=&v"(Uz[1]), "=&v"(Uz[2]), "=&v"(Uz[3]), "=&v"(Uz[4]),
          "=&v"(Uz[5]), "=&v"(Uz[6]), "=&v"(Uz[7]), "=&v"(Uz[8]), "=&v"(Uz[9]),
          "=&v"(Ur[0]), "=&v"(Ur[1]), "=&v"(Ur[2]), "=&v"(Ur[3]), "=&v"(Ur[4]),
          "=&v"(Ur[5]), "=&v"(Ur[6]), "=&v"(Ur[7]), "=&v"(Ur[8]), "=&v"(Ur[9])
        : "v"(ubase) : "memory");
    float bzc, brc, bhi, brh;
    asm volatile(
        "ds_read_b32 %0, %14 offset:1600\n\t" "ds_read_b32 %1, %14 offset:1680\n\t"
        "ds_read_b32 %2, %14 offset:1760\n\t" "ds_read_b32 %3, %14 offset:1840\n\t"
        "ds_read_b32 %4, %14 offset:1920\n\t" "ds_read_b32 %5, %14 offset:2000\n\t"
        "ds_read_b32 %6, %14 offset:2080\n\t" "ds_read_b32 %7, %14 offset:2160\n\t"
        "ds_read_b32 %8, %14 offset:2240\n\t" "ds_read_b32 %9, %14 offset:2320\n\t"
        "ds_read_b32 %10, %14 offset:2400\n\t" "ds_read_b32 %11, %14 offset:2480\n\t"
        "ds_read_b32 %12, %14 offset:2560\n\t" "ds_read_b32 %13, %14 offset:2640\n\t"
        "s_waitcnt lgkmcnt(0)"
        : "=&v"(Uh[0]), "=&v"(Uh[1]), "=&v"(Uh[2]), "=&v"(Uh[3]), "=&v"(Uh[4]),
          "=&v"(Uh[5]), "=&v"(Uh[6]), "=&v"(Uh[7]), "=&v"(Uh[8]), "=&v"(Uh[9]),
          "=&v"(bzc), "=&v"(brc), "=&v"(bhi), "=&v"(brh)
        : "v"(ubase) : "memory");

    const unsigned hbase = (unsigned)(size_t)&hbuf[0];
    const unsigned waddr = active ? (hbase + 48u * (unsigned)g3a + 2u * (unsigned)j)
                                  : (hbase + 144u + 2u * (unsigned)(lane - 60));
    const unsigned raddr = hbase + 48u * (unsigned)g3;

    const int* xrow = x + bc * TT;

    // prologue: fold x-part for t=0, prefetch xv for t=1
    const int xv0 = xrow[0];
    const float* kw0 = kernelW + xv0 * G3;
    float cz = fmaf(kw0[j],        -L2E,     bzc);
    float cr = fmaf(kw0[HH + j],   -L2E,     brc);
    float ch = fmaf(kw0[2*HH + j], 2.0f*L2E, bhi);
    int xvA = xrow[1];

    float hm = 0.0f;
    v4i p0, p1; v2i p2;
    exch_issue(waddr, 0u, raddr, p0, p1, p2);   // transport h(0)=0

    for (int t = 0; t < TT; ++t) {
        // ---- prefetch (vmcnt, off-chain): kW(t+1) via xvA, xv(t+2)
        const float* kwn = kernelW + xvA * G3;
        const float lz = kwn[j];
        const float lr = kwn[HH + j];
        const float lh = kwn[2*HH + j];
        const int xvB = xrow[(t + 2 < TT) ? (t + 2) : (TT - 1)];

        // ---- pairs 0-3 ready (write+read0 retired): start the dot chains
        exch_wait_first(p0);
        float za = cz,  ra = cr,  ha = brh;
        {
            const unsigned h0 = (unsigned)p0.x, h1 = (unsigned)p0.y,
                           h2 = (unsigned)p0.z, h3 = (unsigned)p0.w;
            za = dot2bf(h0, Uz[0], za); ra = dot2bf(h0, Ur[0], ra); ha = dot2bf(h0, Uh[0], ha);
            za = dot2bf(h1, Uz[1], za); ra = dot2bf(h1, Ur[1], ra); ha = dot2bf(h1, Uh[1], ha);
            za = dot2bf(h2, Uz[2], za); ra = dot2bf(h2, Ur[2], ra); ha = dot2bf(h2, Uh[2], ha);
            za = dot2bf(h3, Uz[3], za); ra = dot2bf(h3, Ur[3], ra); ha = dot2bf(h3, Uh[3], ha);
        }
        // ---- pairs 4-9
        exch_wait_rest(p1, p2);
        const unsigned h4 = (unsigned)p1.x, h5 = (unsigned)p1.y,
                       h6 = (unsigned)p1.z, h7 = (unsigned)p1.w,
                       h8 = (unsigned)p2.x, h9 = (unsigned)p2.y;
        za = dot2bf(h4, Uz[4], za); ra = dot2bf(h4, Ur[4], ra); ha = dot2bf(h4, Uh[4], ha);
        float zb = 0.f, rb = 0.f, hb = 0.f;
        zb = dot2bf(h5, Uz[5], zb); rb = dot2bf(h5, Ur[5], rb); hb = dot2bf(h5, Uh[5], hb);
        zb = dot2bf(h6, Uz[6], zb); rb = dot2bf(h6, Ur[6], rb); hb = dot2bf(h6, Uh[6], hb);
        zb = dot2bf(h7, Uz[7], zb); rb = dot2bf(h7, Ur[7], rb); hb = dot2bf(h7, Uh[7], hb);
        zb = dot2bf(h8, Uz[8], zb); rb = dot2bf(h8, Ur[8], rb); hb = dot2bf(h8, Uh[8], hb);
        zb = dot2bf(h9, Uz[9], zb); rb = dot2bf(h9, Ur[9], rb); hb = dot2bf(h9, Uh[9], hb);

        // ---- folded activations (one v_exp + one v_rcp each)
        const float r  = fast_rcp(1.0f + exp2i(ra + rb));          // sigmoid
        const float z  = fast_rcp(1.0f + exp2i(za + zb));          // sigmoid
        const float yh = fmaf(r, ha + hb, ch);                     // 2log2e-scaled
        const float hc = fmaf(-2.0f, fast_rcp(1.0f + exp2i(yh)), 1.0f); // tanh
        hm = hc + z * (hm - hc);

        // ---- pack and ISSUE next step's exchange (RT hides under glue)
        const unsigned hbf = cvtpk(hm, hm);
        exch_issue(waddr, hbf, raddr, p0, p1, p2);

        // ---- commit prefetched folds for t+1
        cz = fmaf(lz, -L2E,     bzc);
        cr = fmaf(lr, -L2E,     brc);
        ch = fmaf(lh, 2.0f*L2E, bhi);
        xvA = xvB;
    }

    // ---- final exchange (issued at t=255 bottom) carries h(256)
    asm volatile("s_waitcnt lgkmcnt(0)" : "+v"(p0), "+v"(p1), "+v"(p2));
    __builtin_amdgcn_sched_barrier(0);
    const unsigned fp[10] = { (unsigned)p0.x, (unsigned)p0.y, (unsigned)p0.z,
                              (unsigned)p0.w, (unsigned)p1.x, (unsigned)p1.y,
                              (unsigned)p1.z, (unsigned)p1.w, (unsigned)p2.x,
                              (unsigned)p2.y };
    float hf[HH];
    #pragma unroll
    for (int q = 0; q < 10; ++q) {
        hf[2*q]   = __uint_as_float(fp[q] << 16);
        hf[2*q+1] = __uint_as_float(fp[q] & 0xffff0000u);
    }

    // ---- dense head: logits[b][l] = db[l] + sum_i h[i] * W[i][l]
    if (active && j < LL && b < BB) {
        float acc = dense_b[j];
        #pragma unroll
        for (int i = 0; i < HH; ++i)
            acc = fmaf(hf[i], dense_w[i * LL + j], acc);
        out[b * LL + j] = acc;
    }
}

extern "C" void kernel_launch(void* const* d_in, const int* in_sizes, int n_in,
                              void* d_out, int out_size, void* d_ws, size_t ws_size,
                              hipStream_t stream) {
    const int* x            = (const int*)d_in[0];
    // d_in[1] = drop_rate (0.0f) -> dropout is identity; ignored.
    const float* kernelW    = (const float*)d_in[2];
    const float* rkernel    = (const float*)d_in[3];
    const float* bias       = (const float*)d_in[4];
    const float* dense_w    = (const float*)d_in[5];
    const float* dense_b    = (const float*)d_in[6];
    float* out              = (float*)d_out;

    dim3 grid((BB + 2) / 3);   // 1366 one-wave blocks, 3 batches each
    dim3 block(64);
    gru_kernel<<<grid, block, 0, stream>>>(x, kernelW, rkernel, bias,
                                           dense_w, dense_b, out);
}

// Round 17
// 78.044 us; speedup vs baseline: 1.0487x; 1.0034x over previous
//
#include <hip/hip_runtime.h>

// CharRNN GRU: B=4096, T=256, V=256, H=20, L=15, reset_after=True, drop_rate=0.
// f32 in / f32 out. 3 batches per wave (20 lanes each), 1366 one-wave blocks.
// Loop body == R13 (best: pipelined bf16 h-exchange across the backedge with
// counted lgkm waits, v_dot2_f32_bf16 chains, exp2-folded activations).
// NEW: U (30 packed bf16 pairs) + 4 folded bias constants are produced by
// one-time VOLATILE asm ds_reads from an LDS-staged table -> the compiler
// CANNOT rematerialize them (opaque asm), so they must stay VGPR-resident
// (launch_bounds(64,1): 256-VGPR budget, ~75 live, spill unprofitable).
// R6-R15 silently re-fetched U from global every step (VGPR_Count 36-56).

#define BB 4096
#define TT 256
#define VV 256
#define HH 20
#define G3 60    // 3*H
#define LL 15
#define L2E 1.44269504088896340736f

typedef int v4i __attribute__((ext_vector_type(4)));
typedef int v2i __attribute__((ext_vector_type(2)));

static __device__ __forceinline__ unsigned short f2bf(float f) {
    union { float f; unsigned int i; } c; c.f = f;
    unsigned int x = c.i;
    return (unsigned short)((x + 0x7FFFu + ((x >> 16) & 1u)) >> 16); // RNE
}
static __device__ __forceinline__ unsigned pack2bf(float a, float b) {
    return (unsigned)f2bf(a) | ((unsigned)f2bf(b) << 16);
}
static __device__ __forceinline__ float fast_rcp(float x) {
#if __has_builtin(__builtin_amdgcn_rcpf)
    return __builtin_amdgcn_rcpf(x);
#else
    return 1.0f / x;
#endif
}
// D = a.x*b.x + a.y*b.y + c  (bf16 pairs packed in u32, f32 accumulate)
static __device__ __forceinline__ float dot2bf(unsigned a, unsigned b, float c) {
    float d;
    asm("v_dot2_f32_bf16 %0, %1, %2, %3" : "=v"(d) : "v"(a), "v"(b), "v"(c));
    return d;
}
static __device__ __forceinline__ unsigned cvtpk(float lo, float hi) {
    unsigned r;
    asm("v_cvt_pk_bf16_f32 %0, %1, %2" : "=v"(r) : "v"(lo), "v"(hi));
    return r;
}
static __device__ __forceinline__ float exp2i(float x) {
    float r; asm("v_exp_f32 %0, %1" : "=v"(r) : "v"(x)); return r;
}

// issue exchange for the NEXT step: write my bf16 h, queue the 3 reads.
static __device__ __forceinline__ void exch_issue(unsigned waddr, unsigned hbf,
                                                  unsigned raddr,
                                                  v4i& p0, v4i& p1, v2i& p2) {
    asm volatile(
        "ds_write_b16 %3, %4\n\t"
        "ds_read_b128 %0, %5\n\t"
        "ds_read_b128 %1, %5 offset:16\n\t"
        "ds_read_b64 %2, %5 offset:32"
        : "=&v"(p0), "=&v"(p1), "=&v"(p2)
        : "v"(waddr), "v"(hbf), "v"(raddr));
}
static __device__ __forceinline__ void exch_wait_first(v4i& p0) {
    asm volatile("s_waitcnt lgkmcnt(2)" : "+v"(p0));   // write+read0 retired
    __builtin_amdgcn_sched_barrier(0);
}
static __device__ __forceinline__ void exch_wait_rest(v4i& p1, v2i& p2) {
    asm volatile("s_waitcnt lgkmcnt(0)" : "+v"(p1), "+v"(p2));
    __builtin_amdgcn_sched_barrier(0);
}

__global__ __launch_bounds__(64, 1) void gru_kernel(
    const int* __restrict__ x,            // [B][T] int32
    const float* __restrict__ kernelW,    // [V][3H] f32
    const float* __restrict__ rkernel,    // [H][3H] f32
    const float* __restrict__ bias,       // [2][3H] f32
    const float* __restrict__ dense_w,    // [H][L] f32
    const float* __restrict__ dense_b,    // [L] f32
    float* __restrict__ out)              // [B][L] f32
{
    __shared__ __align__(16) unsigned short hbuf[80];  // 160 B h exchange
    // U table: words [0..599] = packed bf16 pairs, idx=(kind*10+q)*20+j
    //          words [600..679] = folded bias f32, idx=600+k*20+j
    __shared__ __align__(16) unsigned utab[680];

    const int lane = threadIdx.x;          // one wave per block
    const int g3a  = lane / 20;            // 0,1,2 active; 3 for lanes 60-63
    const int g3   = (lane < 60) ? g3a : 0;
    const int j    = lane - g3a * 20;      // 0..19 (idle lanes: 0..3)
    const bool active = (lane < 60);
    const long b  = (long)blockIdx.x * 3 + g3;
    const long bc = (b < BB) ? b : (BB - 1);   // clamped for loads

    // ---- stage the pre-scaled tables into LDS (one-time) ----
    for (int idx = lane; idx < 680; idx += 64) {
        float v;
        if (idx < 600) {
            const int kind = idx / 200, rem = idx - kind * 200;
            const int q = rem / 20, jj = rem - q * 20;
            const int off = kind * HH;                      // 0, H, 2H
            const float sc = (kind == 2) ? (2.0f * L2E) : (-L2E);
            utab[idx] = pack2bf(rkernel[(2*q)*G3 + off + jj]   * sc,
                                rkernel[(2*q+1)*G3 + off + jj] * sc);
            continue;
        }
        const int k = (idx - 600) / 20, jj = (idx - 600) - k * 20;
        if      (k == 0) v = (bias[jj]      + bias[G3 + jj])      * (-L2E);
        else if (k == 1) v = (bias[HH + jj] + bias[G3 + HH + jj]) * (-L2E);
        else if (k == 2) v = bias[2*HH + jj]                      * (2.0f*L2E);
        else             v = bias[G3 + 2*HH + jj]                 * (2.0f*L2E);
        utab[idx] = __float_as_uint(v);
    }
    // single wave: DS pipe is in-order, volatile asm reads below see the
    // writes; "memory" clobber stops the compiler sinking stores past them.

    const unsigned ubase = (unsigned)(size_t)&utab[0] + 4u * (unsigned)j;

    // ---- one-time opaque register fill: U pairs + bias constants ----
    unsigned Uz[10], Ur[10], Uh[10];
    asm volatile(
        "ds_read_b32 %0, %20 offset:0\n\t"   "ds_read_b32 %1, %20 offset:80\n\t"
        "ds_read_b32 %2, %20 offset:160\n\t" "ds_read_b32 %3, %20 offset:240\n\t"
        "ds_read_b32 %4, %20 offset:320\n\t" "ds_read_b32 %5, %20 offset:400\n\t"
        "ds_read_b32 %6, %20 offset:480\n\t" "ds_read_b32 %7, %20 offset:560\n\t"
        "ds_read_b32 %8, %20 offset:640\n\t" "ds_read_b32 %9, %20 offset:720\n\t"
        "ds_read_b32 %10, %20 offset:800\n\t" "ds_read_b32 %11, %20 offset:880\n\t"
        "ds_read_b32 %12, %20 offset:960\n\t" "ds_read_b32 %13, %20 offset:1040\n\t"
        "ds_read_b32 %14, %20 offset:1120\n\t" "ds_read_b32 %15, %20 offset:1200\n\t"
        "ds_read_b32 %16, %20 offset:1280\n\t" "ds_read_b32 %17, %20 offset:1360\n\t"
        "ds_read_b32 %18, %20 offset:1440\n\t" "ds_read_b32 %19, %20 offset:1520"
        : "=&v"(Uz[0]), "=&v"(Uz[1]), "=&v"(Uz[2]), "=&v"(Uz[3]), "=&v"(Uz[4]),
          "=&v"(Uz[5]), "=&v"(Uz[6]), "=&v"(Uz[7]), "=&v"(Uz[8]), "=&v"(Uz[9]),
          "=&v"(Ur[0]), "=&v"(Ur[1]), "=&v"(Ur[2]), "=&v"(Ur[3]), "=&v"(Ur[4]),
          "=&v"(Ur[5]), "=&v"(Ur[6]), "=&v"(Ur[7]), "=&v"(Ur[8]), "=&v"(Ur[9])
        : "v"(ubase) : "memory");
    float bzc, brc, bhi, brh;
    asm volatile(
        "ds_read_b32 %0, %14 offset:1600\n\t" "ds_read_b32 %1, %14 offset:1680\n\t"
        "ds_read_b32 %2, %14 offset:1760\n\t" "ds_read_b32 %3, %14 offset:1840\n\t"
        "ds_read_b32 %4, %14 offset:1920\n\t" "ds_read_b32 %5, %14 offset:2000\n\t"
        "ds_read_b32 %6, %14 offset:2080\n\t" "ds_read_b32 %7, %14 offset:2160\n\t"
        "ds_read_b32 %8, %14 offset:2240\n\t" "ds_read_b32 %9, %14 offset:2320\n\t"
        "ds_read_b32 %10, %14 offset:2400\n\t" "ds_read_b32 %11, %14 offset:2480\n\t"
        "ds_read_b32 %12, %14 offset:2560\n\t" "ds_read_b32 %13, %14 offset:2640\n\t"
        "s_waitcnt lgkmcnt(0)"
        : "=&v"(Uh[0]), "=&v"(Uh[1]), "=&v"(Uh[2]), "=&v"(Uh[3]), "=&v"(Uh[4]),
          "=&v"(Uh[5]), "=&v"(Uh[6]), "=&v"(Uh[7]), "=&v"(Uh[8]), "=&v"(Uh[9]),
          "=&v"(bzc), "=&v"(brc), "=&v"(bhi), "=&v"(brh)
        : "v"(ubase) : "memory");

    const unsigned hbase = (unsigned)(size_t)&hbuf[0];
    const unsigned waddr = active ? (hbase + 48u * (unsigned)g3a + 2u * (unsigned)j)
                                  : (hbase + 144u + 2u * (unsigned)(lane - 60));
    const unsigned raddr = hbase + 48u * (unsigned)g3;

    const int* xrow = x + bc * TT;

    // prologue: fold x-part for t=0, prefetch xv for t=1
    const int xv0 = xrow[0];
    const float* kw0 = kernelW + xv0 * G3;
    float cz = fmaf(kw0[j],        -L2E,     bzc);
    float cr = fmaf(kw0[HH + j],   -L2E,     brc);
    float ch = fmaf(kw0[2*HH + j], 2.0f*L2E, bhi);
    int xvA = xrow[1];

    float hm = 0.0f;
    v4i p0, p1; v2i p2;
    exch_issue(waddr, 0u, raddr, p0, p1, p2);   // transport h(0)=0

    for (int t = 0; t < TT; ++t) {
        // ---- prefetch (vmcnt, off-chain): kW(t+1) via xvA, xv(t+2)
        const float* kwn = kernelW + xvA * G3;
        const float lz = kwn[j];
        const float lr = kwn[HH + j];
        const float lh = kwn[2*HH + j];
        const int xvB = xrow[(t + 2 < TT) ? (t + 2) : (TT - 1)];

        // ---- pairs 0-3 ready (write+read0 retired): start the dot chains
        exch_wait_first(p0);
        float za = cz,  ra = cr,  ha = brh;
        {
            const unsigned h0 = (unsigned)p0.x, h1 = (unsigned)p0.y,
                           h2 = (unsigned)p0.z, h3 = (unsigned)p0.w;
            za = dot2bf(h0, Uz[0], za); ra = dot2bf(h0, Ur[0], ra); ha = dot2bf(h0, Uh[0], ha);
            za = dot2bf(h1, Uz[1], za); ra = dot2bf(h1, Ur[1], ra); ha = dot2bf(h1, Uh[1], ha);
            za = dot2bf(h2, Uz[2], za); ra = dot2bf(h2, Ur[2], ra); ha = dot2bf(h2, Uh[2], ha);
            za = dot2bf(h3, Uz[3], za); ra = dot2bf(h3, Ur[3], ra); ha = dot2bf(h3, Uh[3], ha);
        }
        // ---- pairs 4-9
        exch_wait_rest(p1, p2);
        const unsigned h4 = (unsigned)p1.x, h5 = (unsigned)p1.y,
                       h6 = (unsigned)p1.z, h7 = (unsigned)p1.w,
                       h8 = (unsigned)p2.x, h9 = (unsigned)p2.y;
        za = dot2bf(h4, Uz[4], za); ra = dot2bf(h4, Ur[4], ra); ha = dot2bf(h4, Uh[4], ha);
        float zb = 0.f, rb = 0.f, hb = 0.f;
        zb = dot2bf(h5, Uz[5], zb); rb = dot2bf(h5, Ur[5], rb); hb = dot2bf(h5, Uh[5], hb);
        zb = dot2bf(h6, Uz[6], zb); rb = dot2bf(h6, Ur[6], rb); hb = dot2bf(h6, Uh[6], hb);
        zb = dot2bf(h7, Uz[7], zb); rb = dot2bf(h7, Ur[7], rb); hb = dot2bf(h7, Uh[7], hb);
        zb = dot2bf(h8, Uz[8], zb); rb = dot2bf(h8, Ur[8], rb); hb = dot2bf(h8, Uh[8], hb);
        zb = dot2bf(h9, Uz[9], zb); rb = dot2bf(h9, Ur[9], rb); hb = dot2bf(h9, Uh[9], hb);

        // ---- folded activations (one v_exp + one v_rcp each)
        const float r  = fast_rcp(1.0f + exp2i(ra + rb));          // sigmoid
        const float z  = fast_rcp(1.0f + exp2i(za + zb));          // sigmoid
        const float yh = fmaf(r, ha + hb, ch);                     // 2log2e-scaled
        const float hc = fmaf(-2.0f, fast_rcp(1.0f + exp2i(yh)), 1.0f); // tanh
        hm = hc + z * (hm - hc);

        // ---- pack and ISSUE next step's exchange (RT hides under glue)
        const unsigned hbf = cvtpk(hm, hm);
        exch_issue(waddr, hbf, raddr, p0, p1, p2);

        // ---- commit prefetched folds for t+1
        cz = fmaf(lz, -L2E,     bzc);
        cr = fmaf(lr, -L2E,     brc);
        ch = fmaf(lh, 2.0f*L2E, bhi);
        xvA = xvB;
    }

    // ---- final exchange (issued at t=255 bottom) carries h(256)
    asm volatile("s_waitcnt lgkmcnt(0)" : "+v"(p0), "+v"(p1), "+v"(p2));
    __builtin_amdgcn_sched_barrier(0);
    const unsigned fp[10] = { (unsigned)p0.x, (unsigned)p0.y, (unsigned)p0.z,
                              (unsigned)p0.w, (unsigned)p1.x, (unsigned)p1.y,
                              (unsigned)p1.z, (unsigned)p1.w, (unsigned)p2.x,
                              (unsigned)p2.y };
    float hf[HH];
    #pragma unroll
    for (int q = 0; q < 10; ++q) {
        hf[2*q]   = __uint_as_float(fp[q] << 16);
        hf[2*q+1] = __uint_as_float(fp[q] & 0xffff0000u);
    }

    // ---- dense head: logits[b][l] = db[l] + sum_i h[i] * W[i][l]
    if (active && j < LL && b < BB) {
        float acc = dense_b[j];
        #pragma unroll
        for (int i = 0; i < HH; ++i)
            acc = fmaf(hf[i], dense_w[i * LL + j], acc);
        out[b * LL + j] = acc;
    }
}

extern "C" void kernel_launch(void* const* d_in, const int* in_sizes, int n_in,
                              void* d_out, int out_size, void* d_ws, size_t ws_size,
                              hipStream_t stream) {
    const int* x            = (const int*)d_in[0];
    // d_in[1] = drop_rate (0.0f) -> dropout is identity; ignored.
    const float* kernelW    = (const float*)d_in[2];
    const float* rkernel    = (const float*)d_in[3];
    const float* bias       = (const float*)d_in[4];
    const float* dense_w    = (const float*)d_in[5];
    const float* dense_b    = (const float*)d_in[6];
    float* out              = (float*)d_out;

    dim3 grid((BB + 2) / 3);   // 1366 one-wave blocks, 3 batches each
    dim3 block(64);
    gru_kernel<<<grid, block, 0, stream>>>(x, kernelW, rkernel, bias,
                                           dense_w, dense_b, out);
}